// Round 5
// baseline (464.986 us; speedup 1.0000x reference)
//
#include <hip/hip_runtime.h>
#include <hip/hip_bf16.h>
#include <math.h>

typedef __attribute__((ext_vector_type(8))) short bf16x8;
typedef __attribute__((ext_vector_type(4))) float f32x4;

static __device__ inline ushort f2bf(float f) {
    union { float f; unsigned u; } v; v.f = f;
    unsigned r = (v.u + 0x7fff + ((v.u >> 16) & 1)) >> 16;   // RNE
    return (ushort)r;
}

#define GLD_LDS(g, l) \
    __builtin_amdgcn_global_load_lds( \
        (const __attribute__((address_space(1))) void*)(g), \
        (__attribute__((address_space(3))) void*)(l), 16, 0, 0)

// ---------------------------------------------------------------------------
// x fp32 -> bf16
// ---------------------------------------------------------------------------
__global__ __launch_bounds__(256) void convert_x(
    const float* __restrict__ x, ushort* __restrict__ xb)
{
    const size_t i = ((size_t)blockIdx.x * 256 + threadIdx.x) * 8;
    float4 a = *(const float4*)(x + i);
    float4 b = *(const float4*)(x + i + 4);
    bf16x8 t;
    t[0] = (short)f2bf(a.x); t[1] = (short)f2bf(a.y);
    t[2] = (short)f2bf(a.z); t[3] = (short)f2bf(a.w);
    t[4] = (short)f2bf(b.x); t[5] = (short)f2bf(b.y);
    t[6] = (short)f2bf(b.z); t[7] = (short)f2bf(b.w);
    *(bf16x8*)(xb + i) = t;
}

// ---------------------------------------------------------------------------
// Weights fp32 [K][N] -> Wt bf16 [4096][1024] transposed
// ---------------------------------------------------------------------------
__global__ __launch_bounds__(256) void prep_w(
    const float* __restrict__ Wq, const float* __restrict__ Wkv,
    const float* __restrict__ Wo, ushort* __restrict__ Wt)
{
    const int w = threadIdx.x >> 6;
    const int lane = threadIdx.x & 63;
    const int tile = blockIdx.x * 4 + w;
    const int r0 = (tile >> 4) << 6;
    const int k0 = (tile & 15) << 6;

    const float* src; int ld, c0;
    if (r0 < 1024)      { src = Wq;  ld = 1024; c0 = r0; }
    else if (r0 < 3072) { src = Wkv; ld = 2048; c0 = r0 - 1024; }
    else                { src = Wo;  ld = 1024; c0 = r0 - 3072; }

    ushort v[64];
    #pragma unroll
    for (int k = 0; k < 64; ++k)
        v[k] = f2bf(src[(size_t)(k0 + k) * ld + c0 + lane]);

    ushort* dst = Wt + (size_t)(r0 + lane) * 1024 + k0;
    #pragma unroll
    for (int k = 0; k < 64; k += 8) {
        bf16x8 t;
        #pragma unroll
        for (int j = 0; j < 8; ++j) t[j] = (short)v[k + j];
        *(bf16x8*)(dst + k) = t;
    }
}

// ---------------------------------------------------------------------------
// m97-style bf16 MFMA GEMM main loop (128x128 tile, BK=32)
// ---------------------------------------------------------------------------
#define GEMM_MAIN_LOOP(Aptr, Btptr)                                            \
    __shared__ ushort As[128 * 32];                                            \
    __shared__ ushort Bs[128 * 32];                                            \
    const int tid = threadIdx.x;                                               \
    const int lane = tid & 63;                                                 \
    const int w = tid >> 6;                                                    \
    const int l15 = lane & 15;                                                 \
    const int quad = lane >> 4;                                                \
    const int wm = w & 1, wn = w >> 1;                                         \
    const int rowBase = blockIdx.y * 128;                                      \
    const int colBase = blockIdx.x * 128;                                      \
    const int sRow = lane >> 2;                                                \
    const int sOff = (lane & 3) * 8;                                           \
    const ushort* aG0 = (Aptr) + (size_t)(rowBase + (w*2+0)*16 + sRow) * 1024 + sOff; \
    const ushort* aG1 = (Aptr) + (size_t)(rowBase + (w*2+1)*16 + sRow) * 1024 + sOff; \
    const ushort* bG0 = (Btptr) + (size_t)(colBase + (w*2+0)*16 + sRow) * 1024 + sOff; \
    const ushort* bG1 = (Btptr) + (size_t)(colBase + (w*2+1)*16 + sRow) * 1024 + sOff; \
    ushort* aL0 = As + (w*2+0)*512;                                            \
    ushort* aL1 = As + (w*2+1)*512;                                            \
    ushort* bL0 = Bs + (w*2+0)*512;                                            \
    ushort* bL1 = Bs + (w*2+1)*512;                                            \
    f32x4 acc[4][4];                                                           \
    _Pragma("unroll")                                                          \
    for (int i = 0; i < 4; ++i)                                                \
        _Pragma("unroll")                                                      \
        for (int j = 0; j < 4; ++j) acc[i][j] = (f32x4){0.f,0.f,0.f,0.f};      \
    for (int k0 = 0; k0 < 1024; k0 += 32) {                                    \
        __syncthreads();                                                       \
        GLD_LDS(aG0 + k0, aL0);                                                \
        GLD_LDS(aG1 + k0, aL1);                                                \
        GLD_LDS(bG0 + k0, bL0);                                                \
        GLD_LDS(bG1 + k0, bL1);                                                \
        __syncthreads();                                                       \
        bf16x8 af[4], bf[4];                                                   \
        _Pragma("unroll")                                                      \
        for (int mi = 0; mi < 4; ++mi)                                         \
            af[mi] = *(const bf16x8*)&As[(wm*64 + mi*16 + l15)*32 + quad*8];   \
        _Pragma("unroll")                                                      \
        for (int ni = 0; ni < 4; ++ni)                                         \
            bf[ni] = *(const bf16x8*)&Bs[(wn*64 + ni*16 + l15)*32 + quad*8];   \
        _Pragma("unroll")                                                      \
        for (int mi = 0; mi < 4; ++mi)                                         \
            _Pragma("unroll")                                                  \
            for (int ni = 0; ni < 4; ++ni)                                     \
                acc[mi][ni] = __builtin_amdgcn_mfma_f32_16x16x32_bf16(         \
                    af[mi], bf[ni], acc[mi][ni], 0, 0, 0);                     \
    }

// ---------------------------------------------------------------------------
// GEMM 1: xb x Wt[0:3072] -> Q (pre-scaled by 0.125*log2e), K in [bh][n][64];
//         V directly transposed into Vt [bh*64+d][2048]
// ---------------------------------------------------------------------------
__global__ __launch_bounds__(256) void gemm_qkv(
    const ushort* __restrict__ A, const ushort* __restrict__ Bt,
    ushort* __restrict__ Qb, ushort* __restrict__ Kb, ushort* __restrict__ Vt)
{
    GEMM_MAIN_LOOP(A, Bt)

    const int seg = colBase >> 10;          // 0=Q 1=K 2=V
    if (seg == 2) {
        #pragma unroll
        for (int mi = 0; mi < 4; ++mi) {
            #pragma unroll
            for (int ni = 0; ni < 4; ++ni) {
                const int c = (colBase + wn*64 + ni*16 + l15) & 1023;
                const int h = c >> 6, d = c & 63;
                const int m = rowBase + wm*64 + mi*16 + quad*4;
                const int b = m >> 11, nn = m & 2047;
                ushort4 v;
                v.x = f2bf(acc[mi][ni][0]); v.y = f2bf(acc[mi][ni][1]);
                v.z = f2bf(acc[mi][ni][2]); v.w = f2bf(acc[mi][ni][3]);
                *(ushort4*)(Vt + ((size_t)(b*16 + h)*64 + d)*2048 + nn) = v;
            }
        }
    } else {
        ushort* dst = seg ? Kb : Qb;
        // Q pre-scale: 1/sqrt(64) * log2(e)  (softmax runs in base-2 domain)
        const float sc = seg ? 1.0f : 0.18033688011112042f;
        #pragma unroll
        for (int mi = 0; mi < 4; ++mi) {
            #pragma unroll
            for (int ni = 0; ni < 4; ++ni) {
                const int c = (colBase + wn*64 + ni*16 + l15) & 1023;
                const int h = c >> 6, d = c & 63;
                #pragma unroll
                for (int r = 0; r < 4; ++r) {
                    const int m = rowBase + wm*64 + mi*16 + quad*4 + r;
                    const int b = m >> 11, nn = m & 2047;
                    dst[((((size_t)b*16 + h)*2048 + nn) << 6) + d] = f2bf(acc[mi][ni][r] * sc);
                }
            }
        }
    }
}

// ---------------------------------------------------------------------------
// GEMM 2: Ob x Wt[3072:4096] + bo -> fp32 out
// ---------------------------------------------------------------------------
__global__ __launch_bounds__(256) void gemm_out(
    const ushort* __restrict__ A, const ushort* __restrict__ Bt,
    const float* __restrict__ bo, float* __restrict__ out)
{
    GEMM_MAIN_LOOP(A, Bt)

    #pragma unroll
    for (int mi = 0; mi < 4; ++mi) {
        #pragma unroll
        for (int ni = 0; ni < 4; ++ni) {
            const int n = colBase + wn*64 + ni*16 + l15;
            const float bb = bo[n];
            #pragma unroll
            for (int r = 0; r < 4; ++r) {
                const int m = rowBase + wm*64 + mi*16 + quad*4 + r;
                out[(size_t)m * 1024 + n] = acc[mi][ni][r] + bb;
            }
        }
    }
}

// ---------------------------------------------------------------------------
// MFMA flash attention v3: barrier-free, per-wave register prefetch.
// Block = 4 independent waves x 32 q-rows. K/V frags from global (L2-hot),
// ping-pong prefetched one 64-key tile ahead. l via MFMA ones-column trick.
// Softmax in base-2 domain (Q pre-scaled by 0.125*log2e).
// ---------------------------------------------------------------------------
__device__ __forceinline__ void fa_tile(
    int j0, int rb0, int l15, int quad,
    const bf16x8 qf[2][2], const bf16x8 kf[4][2], const bf16x8 vf[4][2],
    const bf16x8& bones, float m_r[2][4], f32x4 o[2][4], f32x4 lacc[2],
    ushort (*Ps)[72])
{
    if (j0 > rb0 + 31) return;          // wave-uniform

    // ---- S = Q K^T (32 x 64) ----
    f32x4 S[2][4];
    #pragma unroll
    for (int cb = 0; cb < 4; ++cb) {
        #pragma unroll
        for (int mi = 0; mi < 2; ++mi) {
            f32x4 s = (f32x4){0.f, 0.f, 0.f, 0.f};
            s = __builtin_amdgcn_mfma_f32_16x16x32_bf16(qf[mi][0], kf[cb][0], s, 0, 0, 0);
            s = __builtin_amdgcn_mfma_f32_16x16x32_bf16(qf[mi][1], kf[cb][1], s, 0, 0, 0);
            S[mi][cb] = s;
        }
    }

    #pragma unroll
    for (int mi = 0; mi < 2; ++mi) {
        const int rbase = rb0 + mi * 16;
        // causal mask (diagonal-straddling tiles only)
        if (j0 + 63 > rbase) {
            #pragma unroll
            for (int cb = 0; cb < 4; ++cb) {
                const int jg = j0 + cb * 16 + l15;
                #pragma unroll
                for (int r = 0; r < 4; ++r)
                    if (jg > rbase + quad * 4 + r) S[mi][cb][r] = -INFINITY;
            }
        }
        // online softmax (base-2); row sum deferred to MFMA ones-trick
        #pragma unroll
        for (int r = 0; r < 4; ++r) {
            float mx = fmaxf(fmaxf(S[mi][0][r], S[mi][1][r]),
                             fmaxf(S[mi][2][r], S[mi][3][r]));
            mx = fmaxf(mx, __shfl_xor(mx, 1));
            mx = fmaxf(mx, __shfl_xor(mx, 2));
            mx = fmaxf(mx, __shfl_xor(mx, 4));
            mx = fmaxf(mx, __shfl_xor(mx, 8));
            const float mnew = fmaxf(m_r[mi][r], mx);
            const float corr = __builtin_amdgcn_exp2f(m_r[mi][r] - mnew);
            m_r[mi][r] = mnew;
            #pragma unroll
            for (int cb = 0; cb < 4; ++cb)
                S[mi][cb][r] = __builtin_amdgcn_exp2f(S[mi][cb][r] - mnew);
            lacc[mi][r] *= corr;
            #pragma unroll
            for (int nb = 0; nb < 4; ++nb) o[mi][nb][r] *= corr;
        }
        // P -> per-wave LDS (truncating cast; consistent num/denom quantization)
        #pragma unroll
        for (int cb = 0; cb < 4; ++cb)
            #pragma unroll
            for (int r = 0; r < 4; ++r) {
                union { float f; unsigned u; } cv; cv.f = S[mi][cb][r];
                Ps[mi*16 + quad*4 + r][cb*16 + l15] = (ushort)(cv.u >> 16);
            }
    }

    // ---- O += P V ; l += P . 1 ----
    bf16x8 pf[2][2];
    #pragma unroll
    for (int mi = 0; mi < 2; ++mi) {
        pf[mi][0] = *(const bf16x8*)&Ps[mi*16 + l15][quad * 8];
        pf[mi][1] = *(const bf16x8*)&Ps[mi*16 + l15][32 + quad * 8];
    }
    #pragma unroll
    for (int mi = 0; mi < 2; ++mi) {
        lacc[mi] = __builtin_amdgcn_mfma_f32_16x16x32_bf16(pf[mi][0], bones, lacc[mi], 0, 0, 0);
        lacc[mi] = __builtin_amdgcn_mfma_f32_16x16x32_bf16(pf[mi][1], bones, lacc[mi], 0, 0, 0);
    }
    #pragma unroll
    for (int nb = 0; nb < 4; ++nb) {
        #pragma unroll
        for (int mi = 0; mi < 2; ++mi) {
            o[mi][nb] = __builtin_amdgcn_mfma_f32_16x16x32_bf16(pf[mi][0], vf[nb][0], o[mi][nb], 0, 0, 0);
            o[mi][nb] = __builtin_amdgcn_mfma_f32_16x16x32_bf16(pf[mi][1], vf[nb][1], o[mi][nb], 0, 0, 0);
        }
    }
}

#define LOADK(jt, kf) { \
    const ushort* kb_ = Kb + (size_t)bh * 131072 + (size_t)((jt) << 6) * 64; \
    _Pragma("unroll") \
    for (int cb = 0; cb < 4; ++cb) { \
        const ushort* p_ = kb_ + (cb * 16 + l15) * 64 + quad * 8; \
        kf[cb][0] = *(const bf16x8*)p_; \
        kf[cb][1] = *(const bf16x8*)(p_ + 32); } }

#define LOADV(jt, vf) { \
    const ushort* vb_ = Vt + (size_t)bh * 131072 + ((jt) << 6); \
    _Pragma("unroll") \
    for (int nb = 0; nb < 4; ++nb) { \
        const ushort* p_ = vb_ + (size_t)(nb * 16 + l15) * 2048 + quad * 8; \
        vf[nb][0] = *(const bf16x8*)p_; \
        vf[nb][1] = *(const bf16x8*)(p_ + 32); } }

__global__ __launch_bounds__(256, 2) void flash_mfma(
    const ushort* __restrict__ Qb,
    const ushort* __restrict__ Kb,
    const ushort* __restrict__ Vt,
    ushort* __restrict__ Ob)
{
    __shared__ ushort PsAll[4][32][72];

    const int tid = threadIdx.x;
    const int w = tid >> 6;
    const int lane = tid & 63;
    const int l15 = lane & 15;
    const int quad = lane >> 4;
    ushort (*Ps)[72] = PsAll[w];

    // XCD swizzle: 8 bh per xcd slot; qt descending (long blocks first)
    const int blk = blockIdx.x;
    const int bh = (blk & 7) * 8 + (blk >> 7);
    const int qt = 15 - ((blk >> 3) & 15);
    const int rb0 = (qt << 7) + w * 32;

    // Q fragments (pre-scaled by 0.125*log2e in gemm_qkv)
    bf16x8 qf[2][2];
    #pragma unroll
    for (int mi = 0; mi < 2; ++mi) {
        const ushort* qp = Qb + ((size_t)bh * 2048 + rb0 + mi*16 + l15) * 64 + quad * 8;
        qf[mi][0] = *(const bf16x8*)qp;
        qf[mi][1] = *(const bf16x8*)(qp + 32);
    }

    bf16x8 bones;
    #pragma unroll
    for (int j = 0; j < 8; ++j) bones[j] = (short)0x3F80;   // bf16 1.0

    float m_r[2][4];
    f32x4 o[2][4], lacc[2];
    #pragma unroll
    for (int mi = 0; mi < 2; ++mi) {
        lacc[mi] = (f32x4){0.f, 0.f, 0.f, 0.f};
        #pragma unroll
        for (int r = 0; r < 4; ++r) m_r[mi][r] = -INFINITY;
        #pragma unroll
        for (int nb = 0; nb < 4; ++nb) o[mi][nb] = (f32x4){0.f, 0.f, 0.f, 0.f};
    }

    // per-wave tile count, padded to even for the pair-unrolled loop
    const int nt = ((((rb0 + 31) >> 6) + 1) + 1) & ~1;

    bf16x8 kA[4][2], vA[4][2], kB[4][2], vB[4][2];
    LOADK(0, kA); LOADV(0, vA);

    for (int jt = 0; jt < nt; jt += 2) {
        LOADK(jt + 1, kB); LOADV(jt + 1, vB);
        fa_tile(jt << 6, rb0, l15, quad, qf, kA, vA, bones, m_r, o, lacc, Ps);
        if (jt + 2 < nt) { LOADK(jt + 2, kA); LOADV(jt + 2, vA); }
        fa_tile((jt + 1) << 6, rb0, l15, quad, qf, kB, vB, bones, m_r, o, lacc, Ps);
    }

    // ---- normalize + store O bf16 [b][n][h*64] ----
    const int b = bh >> 4, h = bh & 15;
    #pragma unroll
    for (int mi = 0; mi < 2; ++mi) {
        #pragma unroll
        for (int r = 0; r < 4; ++r) {
            const int ig = rb0 + mi*16 + quad*4 + r;
            const float inv = 1.f / lacc[mi][r];
            ushort* op = Ob + ((size_t)(b * 2048 + ig)) * 1024 + h * 64 + l15;
            #pragma unroll
            for (int nb = 0; nb < 4; ++nb)
                op[nb * 16] = f2bf(o[mi][nb][r] * inv);
        }
    }
}

// ---------------------------------------------------------------------------
extern "C" void kernel_launch(void* const* d_in, const int* in_sizes, int n_in,
                              void* d_out, int out_size, void* d_ws, size_t ws_size,
                              hipStream_t stream) {
    const float* x   = (const float*)d_in[0];
    const float* Wq  = (const float*)d_in[1];
    const float* Wkv = (const float*)d_in[2];
    const float* Wo  = (const float*)d_in[3];
    const float* bo  = (const float*)d_in[4];
    float* out = (float*)d_out;

    const size_t SEG = (size_t)8388608 * 2;   // 16 MB per bf16 [8192x1024]
    char* ws = (char*)d_ws;
    ushort* xb = (ushort*)(ws);
    ushort* Qb = (ushort*)(ws + SEG);
    ushort* Kb = (ushort*)(ws + SEG * 2);
    ushort* Vt = (ushort*)(ws + SEG * 3);     // [bh*64+d][2048]
    ushort* Ob = (ushort*)(ws + SEG * 4);
    ushort* Wt = (ushort*)(ws + SEG * 5);     // [4096][1024] bf16

    convert_x<<<dim3(4096), 256, 0, stream>>>(x, xb);
    prep_w<<<dim3(256), 256, 0, stream>>>(Wq, Wkv, Wo, Wt);
    gemm_qkv<<<dim3(24, 64), 256, 0, stream>>>(xb, Wt, Qb, Kb, Vt);
    flash_mfma<<<dim3(1024), 256, 0, stream>>>(Qb, Kb, Vt, Ob);
    gemm_out<<<dim3(8, 64), 256, 0, stream>>>(Ob, Wt + (size_t)3072 * 1024, bo, out);
}

// Round 6
// 296.565 us; speedup vs baseline: 1.5679x; 1.5679x over previous
//
#include <hip/hip_runtime.h>
#include <hip/hip_bf16.h>
#include <math.h>

typedef __attribute__((ext_vector_type(8))) short bf16x8;
typedef __attribute__((ext_vector_type(4))) float f32x4;

static __device__ inline ushort f2bf(float f) {
    union { float f; unsigned u; } v; v.f = f;
    unsigned r = (v.u + 0x7fff + ((v.u >> 16) & 1)) >> 16;   // RNE
    return (ushort)r;
}

#define GLD_LDS(g, l) \
    __builtin_amdgcn_global_load_lds( \
        (const __attribute__((address_space(1))) void*)(g), \
        (__attribute__((address_space(3))) void*)(l), 16, 0, 0)

// ---------------------------------------------------------------------------
// x fp32 -> bf16
// ---------------------------------------------------------------------------
__global__ __launch_bounds__(256) void convert_x(
    const float* __restrict__ x, ushort* __restrict__ xb)
{
    const size_t i = ((size_t)blockIdx.x * 256 + threadIdx.x) * 8;
    float4 a = *(const float4*)(x + i);
    float4 b = *(const float4*)(x + i + 4);
    bf16x8 t;
    t[0] = (short)f2bf(a.x); t[1] = (short)f2bf(a.y);
    t[2] = (short)f2bf(a.z); t[3] = (short)f2bf(a.w);
    t[4] = (short)f2bf(b.x); t[5] = (short)f2bf(b.y);
    t[6] = (short)f2bf(b.z); t[7] = (short)f2bf(b.w);
    *(bf16x8*)(xb + i) = t;
}

// ---------------------------------------------------------------------------
// Weights fp32 [K][N] -> Wt bf16 [4096][1024] transposed
// ---------------------------------------------------------------------------
__global__ __launch_bounds__(256) void prep_w(
    const float* __restrict__ Wq, const float* __restrict__ Wkv,
    const float* __restrict__ Wo, ushort* __restrict__ Wt)
{
    const int w = threadIdx.x >> 6;
    const int lane = threadIdx.x & 63;
    const int tile = blockIdx.x * 4 + w;
    const int r0 = (tile >> 4) << 6;
    const int k0 = (tile & 15) << 6;

    const float* src; int ld, c0;
    if (r0 < 1024)      { src = Wq;  ld = 1024; c0 = r0; }
    else if (r0 < 3072) { src = Wkv; ld = 2048; c0 = r0 - 1024; }
    else                { src = Wo;  ld = 1024; c0 = r0 - 3072; }

    ushort v[64];
    #pragma unroll
    for (int k = 0; k < 64; ++k)
        v[k] = f2bf(src[(size_t)(k0 + k) * ld + c0 + lane]);

    ushort* dst = Wt + (size_t)(r0 + lane) * 1024 + k0;
    #pragma unroll
    for (int k = 0; k < 64; k += 8) {
        bf16x8 t;
        #pragma unroll
        for (int j = 0; j < 8; ++j) t[j] = (short)v[k + j];
        *(bf16x8*)(dst + k) = t;
    }
}

// ---------------------------------------------------------------------------
// m97-style bf16 MFMA GEMM main loop (128x128 tile, BK=32)
// ---------------------------------------------------------------------------
#define GEMM_MAIN_LOOP(Aptr, Btptr)                                            \
    __shared__ ushort As[128 * 32];                                            \
    __shared__ ushort Bs[128 * 32];                                            \
    const int tid = threadIdx.x;                                               \
    const int lane = tid & 63;                                                 \
    const int w = tid >> 6;                                                    \
    const int l15 = lane & 15;                                                 \
    const int quad = lane >> 4;                                                \
    const int wm = w & 1, wn = w >> 1;                                         \
    const int rowBase = blockIdx.y * 128;                                      \
    const int colBase = blockIdx.x * 128;                                      \
    const int sRow = lane >> 2;                                                \
    const int sOff = (lane & 3) * 8;                                           \
    const ushort* aG0 = (Aptr) + (size_t)(rowBase + (w*2+0)*16 + sRow) * 1024 + sOff; \
    const ushort* aG1 = (Aptr) + (size_t)(rowBase + (w*2+1)*16 + sRow) * 1024 + sOff; \
    const ushort* bG0 = (Btptr) + (size_t)(colBase + (w*2+0)*16 + sRow) * 1024 + sOff; \
    const ushort* bG1 = (Btptr) + (size_t)(colBase + (w*2+1)*16 + sRow) * 1024 + sOff; \
    ushort* aL0 = As + (w*2+0)*512;                                            \
    ushort* aL1 = As + (w*2+1)*512;                                            \
    ushort* bL0 = Bs + (w*2+0)*512;                                            \
    ushort* bL1 = Bs + (w*2+1)*512;                                            \
    f32x4 acc[4][4];                                                           \
    _Pragma("unroll")                                                          \
    for (int i = 0; i < 4; ++i)                                                \
        _Pragma("unroll")                                                      \
        for (int j = 0; j < 4; ++j) acc[i][j] = (f32x4){0.f,0.f,0.f,0.f};      \
    for (int k0 = 0; k0 < 1024; k0 += 32) {                                    \
        __syncthreads();                                                       \
        GLD_LDS(aG0 + k0, aL0);                                                \
        GLD_LDS(aG1 + k0, aL1);                                                \
        GLD_LDS(bG0 + k0, bL0);                                                \
        GLD_LDS(bG1 + k0, bL1);                                                \
        __syncthreads();                                                       \
        bf16x8 af[4], bf[4];                                                   \
        _Pragma("unroll")                                                      \
        for (int mi = 0; mi < 4; ++mi)                                         \
            af[mi] = *(const bf16x8*)&As[(wm*64 + mi*16 + l15)*32 + quad*8];   \
        _Pragma("unroll")                                                      \
        for (int ni = 0; ni < 4; ++ni)                                         \
            bf[ni] = *(const bf16x8*)&Bs[(wn*64 + ni*16 + l15)*32 + quad*8];   \
        _Pragma("unroll")                                                      \
        for (int mi = 0; mi < 4; ++mi)                                         \
            _Pragma("unroll")                                                  \
            for (int ni = 0; ni < 4; ++ni)                                     \
                acc[mi][ni] = __builtin_amdgcn_mfma_f32_16x16x32_bf16(         \
                    af[mi], bf[ni], acc[mi][ni], 0, 0, 0);                     \
    }

// ---------------------------------------------------------------------------
// GEMM 1: xb x Wt[0:3072] -> Q (pre-scaled by 0.125*log2e), K in [bh][n][64];
//         V directly transposed into Vt [bh*64+d][2048]
// ---------------------------------------------------------------------------
__global__ __launch_bounds__(256) void gemm_qkv(
    const ushort* __restrict__ A, const ushort* __restrict__ Bt,
    ushort* __restrict__ Qb, ushort* __restrict__ Kb, ushort* __restrict__ Vt)
{
    GEMM_MAIN_LOOP(A, Bt)

    const int seg = colBase >> 10;          // 0=Q 1=K 2=V
    if (seg == 2) {
        #pragma unroll
        for (int mi = 0; mi < 4; ++mi) {
            #pragma unroll
            for (int ni = 0; ni < 4; ++ni) {
                const int c = (colBase + wn*64 + ni*16 + l15) & 1023;
                const int h = c >> 6, d = c & 63;
                const int m = rowBase + wm*64 + mi*16 + quad*4;
                const int b = m >> 11, nn = m & 2047;
                ushort4 v;
                v.x = f2bf(acc[mi][ni][0]); v.y = f2bf(acc[mi][ni][1]);
                v.z = f2bf(acc[mi][ni][2]); v.w = f2bf(acc[mi][ni][3]);
                *(ushort4*)(Vt + ((size_t)(b*16 + h)*64 + d)*2048 + nn) = v;
            }
        }
    } else {
        ushort* dst = seg ? Kb : Qb;
        // Q pre-scale: 1/sqrt(64) * log2(e)  (softmax runs in base-2 domain)
        const float sc = seg ? 1.0f : 0.18033688011112042f;
        #pragma unroll
        for (int mi = 0; mi < 4; ++mi) {
            #pragma unroll
            for (int ni = 0; ni < 4; ++ni) {
                const int c = (colBase + wn*64 + ni*16 + l15) & 1023;
                const int h = c >> 6, d = c & 63;
                #pragma unroll
                for (int r = 0; r < 4; ++r) {
                    const int m = rowBase + wm*64 + mi*16 + quad*4 + r;
                    const int b = m >> 11, nn = m & 2047;
                    dst[((((size_t)b*16 + h)*2048 + nn) << 6) + d] = f2bf(acc[mi][ni][r] * sc);
                }
            }
        }
    }
}

// ---------------------------------------------------------------------------
// GEMM 2: Ob x Wt[3072:4096] + bo -> fp32 out
// ---------------------------------------------------------------------------
__global__ __launch_bounds__(256) void gemm_out(
    const ushort* __restrict__ A, const ushort* __restrict__ Bt,
    const float* __restrict__ bo, float* __restrict__ out)
{
    GEMM_MAIN_LOOP(A, Bt)

    #pragma unroll
    for (int mi = 0; mi < 4; ++mi) {
        #pragma unroll
        for (int ni = 0; ni < 4; ++ni) {
            const int n = colBase + wn*64 + ni*16 + l15;
            const float bb = bo[n];
            #pragma unroll
            for (int r = 0; r < 4; ++r) {
                const int m = rowBase + wm*64 + mi*16 + quad*4 + r;
                out[(size_t)m * 1024 + n] = acc[mi][ni][r] + bb;
            }
        }
    }
}

// ---------------------------------------------------------------------------
// Flash attention v4: S^T trick + paired q-tiles (perfect balance) +
// double-buffered LDS K/V staging (one barrier/iter).
// Block = 4 waves x 32 q-rows; handles q-tile (15-p) then q-tile p.
// ---------------------------------------------------------------------------
__device__ __forceinline__ bf16x8 lds_frag(const ushort* S, int row, int chunk) {
    return *(const bf16x8*)(S + row * 64 + ((chunk ^ (row & 7)) << 3));
}

__global__ __launch_bounds__(256, 2) void flash_mfma(
    const ushort* __restrict__ Qb,
    const ushort* __restrict__ Kb,
    const ushort* __restrict__ Vt,
    ushort* __restrict__ Ob)
{
    __shared__ ushort Ks[2][4096];
    __shared__ ushort Vs[2][4096];
    __shared__ ushort PsAll[4][32][72];

    const int tid = threadIdx.x;
    const int w = tid >> 6;
    const int lane = tid & 63;
    const int l15 = lane & 15;
    const int quad = lane >> 4;
    ushort (*Ps)[72] = PsAll[w];

    // 512 blocks: [p:3][bh_hi:3][xcd:3]; 8 heads per XCD slot (4MB K+V in L2)
    const int blk = blockIdx.x;
    const int bh = ((blk & 7) << 3) | ((blk >> 3) & 7);
    const int p = blk >> 6;                  // pair index 0..7
    const int qtHi = 15 - p, qtLo = p;
    const int ntHi = 2 * qtHi + 2;
    const int total = 34;                    // ntHi + ntLo, uniform

    const int rb[2] = { (qtHi << 7) + w * 32, (qtLo << 7) + w * 32 };

    // staging maps (xor-swizzled, 2x 16B chunks per thread per buffer)
    const int sr0 = tid >> 3, sr1 = sr0 + 32;
    const int cg0 = (tid & 7) ^ (sr0 & 7);
    const int cg1 = (tid & 7) ^ (sr1 & 7);
    const ushort* kgb = Kb + (size_t)bh * 131072;
    const ushort* vgb = Vt + (size_t)bh * 131072;

    // Q fragments for both parts (pre-scaled by 0.125*log2e)
    bf16x8 qf[2][2][2];
    #pragma unroll
    for (int p_ = 0; p_ < 2; ++p_)
        #pragma unroll
        for (int mi = 0; mi < 2; ++mi) {
            const ushort* qp = Qb + ((size_t)bh * 2048 + rb[p_] + mi*16 + l15) * 64 + quad * 8;
            qf[p_][mi][0] = *(const bf16x8*)qp;
            qf[p_][mi][1] = *(const bf16x8*)(qp + 32);
        }

    bf16x8 bones;
    #pragma unroll
    for (int j = 0; j < 8; ++j) bones[j] = (short)0x3F80;   // bf16 1.0

    float m_r[2][2];
    f32x4 o[2][2][4], lacc[2][2];
    #pragma unroll
    for (int p_ = 0; p_ < 2; ++p_)
        #pragma unroll
        for (int mi = 0; mi < 2; ++mi) {
            m_r[p_][mi] = -INFINITY;
            lacc[p_][mi] = (f32x4){0.f, 0.f, 0.f, 0.f};
            #pragma unroll
            for (int nb = 0; nb < 4; ++nb) o[p_][mi][nb] = (f32x4){0.f, 0.f, 0.f, 0.f};
        }

    // prefetch tile 0 -> buf 0
    GLD_LDS(kgb + 0*4096 + sr0*64 + cg0*8, &Ks[0][tid*8]);
    GLD_LDS(kgb + 0*4096 + sr1*64 + cg1*8, &Ks[0][tid*8 + 2048]);
    GLD_LDS(vgb + (size_t)sr0*2048 + 0*64 + cg0*8, &Vs[0][tid*8]);
    GLD_LDS(vgb + (size_t)sr1*2048 + 0*64 + cg1*8, &Vs[0][tid*8 + 2048]);

    for (int t = 0; t < total; ++t) {
        __syncthreads();                      // drains own GLDs; joins all waves
        const int cur = t & 1;
        if (t + 1 < total) {
            const int tn = t + 1;
            const int jn = (tn < ntHi) ? tn : tn - ntHi;
            ushort* kd = &Ks[cur ^ 1][tid * 8];
            ushort* vd = &Vs[cur ^ 1][tid * 8];
            GLD_LDS(kgb + (size_t)jn*4096 + sr0*64 + cg0*8, kd);
            GLD_LDS(kgb + (size_t)jn*4096 + sr1*64 + cg1*8, kd + 2048);
            GLD_LDS(vgb + (size_t)sr0*2048 + jn*64 + cg0*8, vd);
            GLD_LDS(vgb + (size_t)sr1*2048 + jn*64 + cg1*8, vd + 2048);
        }
        const int p_ = (t >= ntHi);
        const int jt = p_ ? t - ntHi : t;
        const int j0 = jt << 6;
        const int rb0 = rb[p_];
        if (j0 > rb0 + 31) continue;          // wave-uniform; barrier is at loop top

        const ushort* Ksb = Ks[cur];
        const ushort* Vsb = Vs[cur];

        // ---- S^T = K Q^T : [64 keys][32 qrows]; lane holds one qrow (l15) ----
        f32x4 St[2][4];                       // [mi][kb]
        #pragma unroll
        for (int kb = 0; kb < 4; ++kb) {
            bf16x8 ka = lds_frag(Ksb, kb*16 + l15, quad);
            bf16x8 kc = lds_frag(Ksb, kb*16 + l15, quad + 4);
            #pragma unroll
            for (int mi = 0; mi < 2; ++mi) {
                f32x4 s = (f32x4){0.f, 0.f, 0.f, 0.f};
                s = __builtin_amdgcn_mfma_f32_16x16x32_bf16(ka, qf[p_][mi][0], s, 0, 0, 0);
                s = __builtin_amdgcn_mfma_f32_16x16x32_bf16(kc, qf[p_][mi][1], s, 0, 0, 0);
                St[mi][kb] = s;
            }
        }

        #pragma unroll
        for (int mi = 0; mi < 2; ++mi) {
            const int qrow = rb0 + mi*16 + l15;
            if (j0 + 63 > rb0 + mi*16) {      // causal mask (straddling tiles only)
                #pragma unroll
                for (int kb = 0; kb < 4; ++kb) {
                    const int kbase = j0 + kb*16 + quad*4;
                    #pragma unroll
                    for (int r = 0; r < 4; ++r)
                        if (kbase + r > qrow) St[mi][kb][r] = -INFINITY;
                }
            }
            // lane-local max over this row's 16 scores + 2 cross-quad shuffles
            f32x4 mv = St[mi][0];
            #pragma unroll
            for (int kb = 1; kb < 4; ++kb)
                #pragma unroll
                for (int r = 0; r < 4; ++r) mv[r] = fmaxf(mv[r], St[mi][kb][r]);
            float mx = fmaxf(fmaxf(mv[0], mv[1]), fmaxf(mv[2], mv[3]));
            mx = fmaxf(mx, __shfl_xor(mx, 16));
            mx = fmaxf(mx, __shfl_xor(mx, 32));
            const float mold = m_r[p_][mi];
            const float mnew = fmaxf(mold, mx);
            m_r[p_][mi] = mnew;
            const float corr = __builtin_amdgcn_exp2f(mold - mnew);
            // exp2 (base-2 domain) — mnew is a lane scalar for all 16 scores
            #pragma unroll
            for (int kb = 0; kb < 4; ++kb)
                #pragma unroll
                for (int r = 0; r < 4; ++r)
                    St[mi][kb][r] = __builtin_amdgcn_exp2f(St[mi][kb][r] - mnew);
            // pack 4 scores -> bf16x4, one ds_write_b64 per kb
            #pragma unroll
            for (int kb = 0; kb < 4; ++kb) {
                union { float f; unsigned u; } c0, c1, c2, c3;
                c0.f = St[mi][kb][0]; c1.f = St[mi][kb][1];
                c2.f = St[mi][kb][2]; c3.f = St[mi][kb][3];
                uint2 pk;
                pk.x = (c0.u >> 16) | (c1.u & 0xFFFF0000u);
                pk.y = (c2.u >> 16) | (c3.u & 0xFFFF0000u);
                *(uint2*)&Ps[mi*16 + l15][kb*16 + quad*4] = pk;
            }
            // corr -> O-register layout (rows quad*4+r live in lanes 0..15)
            float ct[4];
            #pragma unroll
            for (int r = 0; r < 4; ++r) ct[r] = __shfl(corr, quad*4 + r);
            #pragma unroll
            for (int r = 0; r < 4; ++r) lacc[p_][mi][r] *= ct[r];
            #pragma unroll
            for (int nb = 0; nb < 4; ++nb)
                #pragma unroll
                for (int r = 0; r < 4; ++r) o[p_][mi][nb][r] *= ct[r];
        }

        // ---- O += P V ; l += P . 1 ----
        bf16x8 pf[2][2];
        #pragma unroll
        for (int mi = 0; mi < 2; ++mi) {
            pf[mi][0] = *(const bf16x8*)&Ps[mi*16 + l15][quad * 8];
            pf[mi][1] = *(const bf16x8*)&Ps[mi*16 + l15][32 + quad * 8];
        }
        #pragma unroll
        for (int mi = 0; mi < 2; ++mi) {
            lacc[p_][mi] = __builtin_amdgcn_mfma_f32_16x16x32_bf16(pf[mi][0], bones, lacc[p_][mi], 0, 0, 0);
            lacc[p_][mi] = __builtin_amdgcn_mfma_f32_16x16x32_bf16(pf[mi][1], bones, lacc[p_][mi], 0, 0, 0);
        }
        #pragma unroll
        for (int nb = 0; nb < 4; ++nb) {
            bf16x8 va = lds_frag(Vsb, nb*16 + l15, quad);
            bf16x8 vc = lds_frag(Vsb, nb*16 + l15, quad + 4);
            #pragma unroll
            for (int mi = 0; mi < 2; ++mi) {
                o[p_][mi][nb] = __builtin_amdgcn_mfma_f32_16x16x32_bf16(pf[mi][0], va, o[p_][mi][nb], 0, 0, 0);
                o[p_][mi][nb] = __builtin_amdgcn_mfma_f32_16x16x32_bf16(pf[mi][1], vc, o[p_][mi][nb], 0, 0, 0);
            }
        }
    }

    // ---- normalize + store O bf16 [b][n][h*64], both parts ----
    const int b = bh >> 4, h = bh & 15;
    #pragma unroll
    for (int p_ = 0; p_ < 2; ++p_)
        #pragma unroll
        for (int mi = 0; mi < 2; ++mi)
            #pragma unroll
            for (int r = 0; r < 4; ++r) {
                const int ig = rb[p_] + mi*16 + quad*4 + r;
                const float inv = 1.f / lacc[p_][mi][r];
                ushort* op = Ob + ((size_t)(b * 2048 + ig)) * 1024 + h * 64 + l15;
                #pragma unroll
                for (int nb = 0; nb < 4; ++nb)
                    op[nb * 16] = f2bf(o[p_][mi][nb][r] * inv);
            }
}

// ---------------------------------------------------------------------------
extern "C" void kernel_launch(void* const* d_in, const int* in_sizes, int n_in,
                              void* d_out, int out_size, void* d_ws, size_t ws_size,
                              hipStream_t stream) {
    const float* x   = (const float*)d_in[0];
    const float* Wq  = (const float*)d_in[1];
    const float* Wkv = (const float*)d_in[2];
    const float* Wo  = (const float*)d_in[3];
    const float* bo  = (const float*)d_in[4];
    float* out = (float*)d_out;

    const size_t SEG = (size_t)8388608 * 2;   // 16 MB per bf16 [8192x1024]
    char* ws = (char*)d_ws;
    ushort* xb = (ushort*)(ws);
    ushort* Qb = (ushort*)(ws + SEG);
    ushort* Kb = (ushort*)(ws + SEG * 2);
    ushort* Vt = (ushort*)(ws + SEG * 3);     // [bh*64+d][2048]
    ushort* Ob = (ushort*)(ws + SEG * 4);
    ushort* Wt = (ushort*)(ws + SEG * 5);     // [4096][1024] bf16

    convert_x<<<dim3(4096), 256, 0, stream>>>(x, xb);
    prep_w<<<dim3(256), 256, 0, stream>>>(Wq, Wkv, Wo, Wt);
    gemm_qkv<<<dim3(24, 64), 256, 0, stream>>>(xb, Wt, Qb, Kb, Vt);
    flash_mfma<<<dim3(512), 256, 0, stream>>>(Qb, Kb, Vt, Ob);
    gemm_out<<<dim3(8, 64), 256, 0, stream>>>(Ob, Wt + (size_t)3072 * 1024, bo, out);
}

// Round 7
// 259.553 us; speedup vs baseline: 1.7915x; 1.1426x over previous
//
#include <hip/hip_runtime.h>
#include <hip/hip_bf16.h>
#include <math.h>

typedef __attribute__((ext_vector_type(8))) short bf16x8;
typedef __attribute__((ext_vector_type(4))) float f32x4;

static __device__ inline ushort f2bf(float f) {
    union { float f; unsigned u; } v; v.f = f;
    unsigned r = (v.u + 0x7fff + ((v.u >> 16) & 1)) >> 16;   // RNE
    return (ushort)r;
}

#define GLD_LDS(g, l) \
    __builtin_amdgcn_global_load_lds( \
        (const __attribute__((address_space(1))) void*)(g), \
        (__attribute__((address_space(3))) void*)(l), 16, 0, 0)

// ---------------------------------------------------------------------------
// x fp32 -> bf16
// ---------------------------------------------------------------------------
__global__ __launch_bounds__(256) void convert_x(
    const float* __restrict__ x, ushort* __restrict__ xb)
{
    const size_t i = ((size_t)blockIdx.x * 256 + threadIdx.x) * 8;
    float4 a = *(const float4*)(x + i);
    float4 b = *(const float4*)(x + i + 4);
    bf16x8 t;
    t[0] = (short)f2bf(a.x); t[1] = (short)f2bf(a.y);
    t[2] = (short)f2bf(a.z); t[3] = (short)f2bf(a.w);
    t[4] = (short)f2bf(b.x); t[5] = (short)f2bf(b.y);
    t[6] = (short)f2bf(b.z); t[7] = (short)f2bf(b.w);
    *(bf16x8*)(xb + i) = t;
}

// ---------------------------------------------------------------------------
// Weights fp32 [K][N] -> Wt bf16 [4096][1024] transposed
// ---------------------------------------------------------------------------
__global__ __launch_bounds__(256) void prep_w(
    const float* __restrict__ Wq, const float* __restrict__ Wkv,
    const float* __restrict__ Wo, ushort* __restrict__ Wt)
{
    const int w = threadIdx.x >> 6;
    const int lane = threadIdx.x & 63;
    const int tile = blockIdx.x * 4 + w;
    const int r0 = (tile >> 4) << 6;
    const int k0 = (tile & 15) << 6;

    const float* src; int ld, c0;
    if (r0 < 1024)      { src = Wq;  ld = 1024; c0 = r0; }
    else if (r0 < 3072) { src = Wkv; ld = 2048; c0 = r0 - 1024; }
    else                { src = Wo;  ld = 1024; c0 = r0 - 3072; }

    ushort v[64];
    #pragma unroll
    for (int k = 0; k < 64; ++k)
        v[k] = f2bf(src[(size_t)(k0 + k) * ld + c0 + lane]);

    ushort* dst = Wt + (size_t)(r0 + lane) * 1024 + k0;
    #pragma unroll
    for (int k = 0; k < 64; k += 8) {
        bf16x8 t;
        #pragma unroll
        for (int j = 0; j < 8; ++j) t[j] = (short)v[k + j];
        *(bf16x8*)(dst + k) = t;
    }
}

// ---------------------------------------------------------------------------
// m97-style bf16 MFMA GEMM main loop (128x128 tile, BK=32)
// ---------------------------------------------------------------------------
#define GEMM_MAIN_LOOP(Aptr, Btptr)                                            \
    __shared__ ushort As[128 * 32];                                            \
    __shared__ ushort Bs[128 * 32];                                            \
    const int tid = threadIdx.x;                                               \
    const int lane = tid & 63;                                                 \
    const int w = tid >> 6;                                                    \
    const int l15 = lane & 15;                                                 \
    const int quad = lane >> 4;                                                \
    const int wm = w & 1, wn = w >> 1;                                         \
    const int rowBase = blockIdx.y * 128;                                      \
    const int colBase = blockIdx.x * 128;                                      \
    const int sRow = lane >> 2;                                                \
    const int sOff = (lane & 3) * 8;                                           \
    const ushort* aG0 = (Aptr) + (size_t)(rowBase + (w*2+0)*16 + sRow) * 1024 + sOff; \
    const ushort* aG1 = (Aptr) + (size_t)(rowBase + (w*2+1)*16 + sRow) * 1024 + sOff; \
    const ushort* bG0 = (Btptr) + (size_t)(colBase + (w*2+0)*16 + sRow) * 1024 + sOff; \
    const ushort* bG1 = (Btptr) + (size_t)(colBase + (w*2+1)*16 + sRow) * 1024 + sOff; \
    ushort* aL0 = As + (w*2+0)*512;                                            \
    ushort* aL1 = As + (w*2+1)*512;                                            \
    ushort* bL0 = Bs + (w*2+0)*512;                                            \
    ushort* bL1 = Bs + (w*2+1)*512;                                            \
    f32x4 acc[4][4];                                                           \
    _Pragma("unroll")                                                          \
    for (int i = 0; i < 4; ++i)                                                \
        _Pragma("unroll")                                                      \
        for (int j = 0; j < 4; ++j) acc[i][j] = (f32x4){0.f,0.f,0.f,0.f};      \
    for (int k0 = 0; k0 < 1024; k0 += 32) {                                    \
        __syncthreads();                                                       \
        GLD_LDS(aG0 + k0, aL0);                                                \
        GLD_LDS(aG1 + k0, aL1);                                                \
        GLD_LDS(bG0 + k0, bL0);                                                \
        GLD_LDS(bG1 + k0, bL1);                                                \
        __syncthreads();                                                       \
        bf16x8 af[4], bf[4];                                                   \
        _Pragma("unroll")                                                      \
        for (int mi = 0; mi < 4; ++mi)                                         \
            af[mi] = *(const bf16x8*)&As[(wm*64 + mi*16 + l15)*32 + quad*8];   \
        _Pragma("unroll")                                                      \
        for (int ni = 0; ni < 4; ++ni)                                         \
            bf[ni] = *(const bf16x8*)&Bs[(wn*64 + ni*16 + l15)*32 + quad*8];   \
        _Pragma("unroll")                                                      \
        for (int mi = 0; mi < 4; ++mi)                                         \
            _Pragma("unroll")                                                  \
            for (int ni = 0; ni < 4; ++ni)                                     \
                acc[mi][ni] = __builtin_amdgcn_mfma_f32_16x16x32_bf16(         \
                    af[mi], bf[ni], acc[mi][ni], 0, 0, 0);                     \
    }

// ---------------------------------------------------------------------------
// GEMM 1: xb x Wt[0:3072] -> Q (pre-scaled by 0.125*log2e), K in [bh][n][64];
//         V directly transposed into Vt [bh*64+d][2048]
// ---------------------------------------------------------------------------
__global__ __launch_bounds__(256) void gemm_qkv(
    const ushort* __restrict__ A, const ushort* __restrict__ Bt,
    ushort* __restrict__ Qb, ushort* __restrict__ Kb, ushort* __restrict__ Vt)
{
    GEMM_MAIN_LOOP(A, Bt)

    const int seg = colBase >> 10;          // 0=Q 1=K 2=V
    if (seg == 2) {
        #pragma unroll
        for (int mi = 0; mi < 4; ++mi) {
            #pragma unroll
            for (int ni = 0; ni < 4; ++ni) {
                const int c = (colBase + wn*64 + ni*16 + l15) & 1023;
                const int h = c >> 6, d = c & 63;
                const int m = rowBase + wm*64 + mi*16 + quad*4;
                const int b = m >> 11, nn = m & 2047;
                ushort4 v;
                v.x = f2bf(acc[mi][ni][0]); v.y = f2bf(acc[mi][ni][1]);
                v.z = f2bf(acc[mi][ni][2]); v.w = f2bf(acc[mi][ni][3]);
                *(ushort4*)(Vt + ((size_t)(b*16 + h)*64 + d)*2048 + nn) = v;
            }
        }
    } else {
        ushort* dst = seg ? Kb : Qb;
        // Q pre-scale: 1/sqrt(64) * log2(e)  (softmax runs in base-2 domain)
        const float sc = seg ? 1.0f : 0.18033688011112042f;
        #pragma unroll
        for (int mi = 0; mi < 4; ++mi) {
            #pragma unroll
            for (int ni = 0; ni < 4; ++ni) {
                const int c = (colBase + wn*64 + ni*16 + l15) & 1023;
                const int h = c >> 6, d = c & 63;
                #pragma unroll
                for (int r = 0; r < 4; ++r) {
                    const int m = rowBase + wm*64 + mi*16 + quad*4 + r;
                    const int b = m >> 11, nn = m & 2047;
                    dst[((((size_t)b*16 + h)*2048 + nn) << 6) + d] = f2bf(acc[mi][ni][r] * sc);
                }
            }
        }
    }
}

// ---------------------------------------------------------------------------
// GEMM 2: Ob x Wt[3072:4096] + bo -> fp32 out
// ---------------------------------------------------------------------------
__global__ __launch_bounds__(256) void gemm_out(
    const ushort* __restrict__ A, const ushort* __restrict__ Bt,
    const float* __restrict__ bo, float* __restrict__ out)
{
    GEMM_MAIN_LOOP(A, Bt)

    #pragma unroll
    for (int mi = 0; mi < 4; ++mi) {
        #pragma unroll
        for (int ni = 0; ni < 4; ++ni) {
            const int n = colBase + wn*64 + ni*16 + l15;
            const float bb = bo[n];
            #pragma unroll
            for (int r = 0; r < 4; ++r) {
                const int m = rowBase + wm*64 + mi*16 + quad*4 + r;
                out[(size_t)m * 1024 + n] = acc[mi][ni][r] + bb;
            }
        }
    }
}

// ---------------------------------------------------------------------------
// Flash attention v5: unpaired q-tiles (grid 1024, qt-descending dispatch),
// double-buffered LDS K/V, S^T trick, skip-rescale on no-new-max.
// Block = 4 waves x 32 q-rows = one 128-row q-tile.
// ---------------------------------------------------------------------------
__device__ __forceinline__ bf16x8 lds_frag(const ushort* S, int row, int chunk) {
    return *(const bf16x8*)(S + row * 64 + ((chunk ^ (row & 7)) << 3));
}

__global__ __launch_bounds__(256, 2) void flash_mfma(
    const ushort* __restrict__ Qb,
    const ushort* __restrict__ Kb,
    const ushort* __restrict__ Vt,
    ushort* __restrict__ Ob)
{
    __shared__ ushort Ks[2][4096];
    __shared__ ushort Vs[2][4096];
    __shared__ ushort PsAll[4][32][72];

    const int tid = threadIdx.x;
    const int w = tid >> 6;
    const int lane = tid & 63;
    const int l15 = lane & 15;
    const int quad = lane >> 4;
    ushort (*Ps)[72] = PsAll[w];

    // 1024 blocks: [qt:4][bh_hi:3][xcd:3]; qt descending so long blocks first;
    // 8 heads per XCD slot (4MB K+V resident in one L2)
    const int blk = blockIdx.x;
    const int bh = ((blk & 7) << 3) | ((blk >> 3) & 7);
    const int qt = 15 - (blk >> 6);
    const int nt = 2 * qt + 2;
    const int rb0 = (qt << 7) + w * 32;

    // staging maps (xor-swizzled, 2x 16B chunks per thread per buffer)
    const int sr0 = tid >> 3, sr1 = sr0 + 32;
    const int cg0 = (tid & 7) ^ (sr0 & 7);
    const int cg1 = (tid & 7) ^ (sr1 & 7);
    const ushort* kgb = Kb + (size_t)bh * 131072;
    const ushort* vgb = Vt + (size_t)bh * 131072;

    // Q fragments (pre-scaled by 0.125*log2e)
    bf16x8 qf[2][2];
    #pragma unroll
    for (int mi = 0; mi < 2; ++mi) {
        const ushort* qp = Qb + ((size_t)bh * 2048 + rb0 + mi*16 + l15) * 64 + quad * 8;
        qf[mi][0] = *(const bf16x8*)qp;
        qf[mi][1] = *(const bf16x8*)(qp + 32);
    }

    bf16x8 bones;
    #pragma unroll
    for (int j = 0; j < 8; ++j) bones[j] = (short)0x3F80;   // bf16 1.0

    float m_r[2];
    f32x4 o[2][4], lacc[2];
    #pragma unroll
    for (int mi = 0; mi < 2; ++mi) {
        m_r[mi] = -INFINITY;
        lacc[mi] = (f32x4){0.f, 0.f, 0.f, 0.f};
        #pragma unroll
        for (int nb = 0; nb < 4; ++nb) o[mi][nb] = (f32x4){0.f, 0.f, 0.f, 0.f};
    }

    // prefetch tile 0 -> buf 0
    GLD_LDS(kgb + sr0*64 + cg0*8, &Ks[0][tid*8]);
    GLD_LDS(kgb + sr1*64 + cg1*8, &Ks[0][tid*8 + 2048]);
    GLD_LDS(vgb + (size_t)sr0*2048 + cg0*8, &Vs[0][tid*8]);
    GLD_LDS(vgb + (size_t)sr1*2048 + cg1*8, &Vs[0][tid*8 + 2048]);

    for (int t = 0; t < nt; ++t) {
        __syncthreads();                      // drains own GLDs; joins all waves
        const int cur = t & 1;
        if (t + 1 < nt) {
            const int jn = t + 1;
            ushort* kd = &Ks[cur ^ 1][tid * 8];
            ushort* vd = &Vs[cur ^ 1][tid * 8];
            GLD_LDS(kgb + (size_t)jn*4096 + sr0*64 + cg0*8, kd);
            GLD_LDS(kgb + (size_t)jn*4096 + sr1*64 + cg1*8, kd + 2048);
            GLD_LDS(vgb + (size_t)sr0*2048 + jn*64 + cg0*8, vd);
            GLD_LDS(vgb + (size_t)sr1*2048 + jn*64 + cg1*8, vd + 2048);
        }
        const int j0 = t << 6;
        if (j0 > rb0 + 31) continue;          // wave-uniform; barrier is at loop top

        const ushort* Ksb = Ks[cur];
        const ushort* Vsb = Vs[cur];

        // ---- S^T = K Q^T : [64 keys][32 qrows]; lane holds one qrow (l15) ----
        f32x4 St[2][4];                       // [mi][kb]
        #pragma unroll
        for (int kb = 0; kb < 4; ++kb) {
            bf16x8 ka = lds_frag(Ksb, kb*16 + l15, quad);
            bf16x8 kc = lds_frag(Ksb, kb*16 + l15, quad + 4);
            #pragma unroll
            for (int mi = 0; mi < 2; ++mi) {
                f32x4 s = (f32x4){0.f, 0.f, 0.f, 0.f};
                s = __builtin_amdgcn_mfma_f32_16x16x32_bf16(ka, qf[mi][0], s, 0, 0, 0);
                s = __builtin_amdgcn_mfma_f32_16x16x32_bf16(kc, qf[mi][1], s, 0, 0, 0);
                St[mi][kb] = s;
            }
        }

        #pragma unroll
        for (int mi = 0; mi < 2; ++mi) {
            const int qrow = rb0 + mi*16 + l15;
            if (j0 + 63 > rb0 + mi*16) {      // causal mask (straddling tiles only)
                #pragma unroll
                for (int kb = 0; kb < 4; ++kb) {
                    const int kbase = j0 + kb*16 + quad*4;
                    #pragma unroll
                    for (int r = 0; r < 4; ++r)
                        if (kbase + r > qrow) St[mi][kb][r] = -INFINITY;
                }
            }
            // lane-local max over this row's 16 scores + 2 cross-quad shuffles
            f32x4 mv = St[mi][0];
            #pragma unroll
            for (int kb = 1; kb < 4; ++kb)
                #pragma unroll
                for (int r = 0; r < 4; ++r) mv[r] = fmaxf(mv[r], St[mi][kb][r]);
            float mx = fmaxf(fmaxf(mv[0], mv[1]), fmaxf(mv[2], mv[3]));
            mx = fmaxf(mx, __shfl_xor(mx, 16));
            mx = fmaxf(mx, __shfl_xor(mx, 32));
            const float mold = m_r[mi];
            const float mnew = fmaxf(mold, mx);
            // skip-rescale: most tiles don't raise any row max
            if (__any(mnew > mold)) {
                m_r[mi] = mnew;
                const float corr = __builtin_amdgcn_exp2f(mold - mnew);
                // corr -> O-register layout (rows quad*4+r live in lanes 0..15)
                float ct[4];
                #pragma unroll
                for (int r = 0; r < 4; ++r) ct[r] = __shfl(corr, quad*4 + r);
                #pragma unroll
                for (int r = 0; r < 4; ++r) lacc[mi][r] *= ct[r];
                #pragma unroll
                for (int nb = 0; nb < 4; ++nb)
                    #pragma unroll
                    for (int r = 0; r < 4; ++r) o[mi][nb][r] *= ct[r];
            }
            // exp2 (base-2 domain) — mnew is a lane scalar for all 16 scores
            #pragma unroll
            for (int kb = 0; kb < 4; ++kb)
                #pragma unroll
                for (int r = 0; r < 4; ++r)
                    St[mi][kb][r] = __builtin_amdgcn_exp2f(St[mi][kb][r] - mnew);
            // pack 4 scores -> bf16x4, one ds_write_b64 per kb
            #pragma unroll
            for (int kb = 0; kb < 4; ++kb) {
                union { float f; unsigned u; } c0, c1, c2, c3;
                c0.f = St[mi][kb][0]; c1.f = St[mi][kb][1];
                c2.f = St[mi][kb][2]; c3.f = St[mi][kb][3];
                uint2 pk;
                pk.x = (c0.u >> 16) | (c1.u & 0xFFFF0000u);
                pk.y = (c2.u >> 16) | (c3.u & 0xFFFF0000u);
                *(uint2*)&Ps[mi*16 + l15][kb*16 + quad*4] = pk;
            }
        }

        // ---- O += P V ; l += P . 1 ----
        bf16x8 pf[2][2];
        #pragma unroll
        for (int mi = 0; mi < 2; ++mi) {
            pf[mi][0] = *(const bf16x8*)&Ps[mi*16 + l15][quad * 8];
            pf[mi][1] = *(const bf16x8*)&Ps[mi*16 + l15][32 + quad * 8];
        }
        #pragma unroll
        for (int mi = 0; mi < 2; ++mi) {
            lacc[mi] = __builtin_amdgcn_mfma_f32_16x16x32_bf16(pf[mi][0], bones, lacc[mi], 0, 0, 0);
            lacc[mi] = __builtin_amdgcn_mfma_f32_16x16x32_bf16(pf[mi][1], bones, lacc[mi], 0, 0, 0);
        }
        #pragma unroll
        for (int nb = 0; nb < 4; ++nb) {
            bf16x8 va = lds_frag(Vsb, nb*16 + l15, quad);
            bf16x8 vc = lds_frag(Vsb, nb*16 + l15, quad + 4);
            #pragma unroll
            for (int mi = 0; mi < 2; ++mi) {
                o[mi][nb] = __builtin_amdgcn_mfma_f32_16x16x32_bf16(pf[mi][0], va, o[mi][nb], 0, 0, 0);
                o[mi][nb] = __builtin_amdgcn_mfma_f32_16x16x32_bf16(pf[mi][1], vc, o[mi][nb], 0, 0, 0);
            }
        }
    }

    // ---- normalize + store O bf16 [b][n][h*64] ----
    const int b = bh >> 4, h = bh & 15;
    #pragma unroll
    for (int mi = 0; mi < 2; ++mi)
        #pragma unroll
        for (int r = 0; r < 4; ++r) {
            const int ig = rb0 + mi*16 + quad*4 + r;
            const float inv = 1.f / lacc[mi][r];
            ushort* op = Ob + ((size_t)(b * 2048 + ig)) * 1024 + h * 64 + l15;
            #pragma unroll
            for (int nb = 0; nb < 4; ++nb)
                op[nb * 16] = f2bf(o[mi][nb][r] * inv);
        }
}

// ---------------------------------------------------------------------------
extern "C" void kernel_launch(void* const* d_in, const int* in_sizes, int n_in,
                              void* d_out, int out_size, void* d_ws, size_t ws_size,
                              hipStream_t stream) {
    const float* x   = (const float*)d_in[0];
    const float* Wq  = (const float*)d_in[1];
    const float* Wkv = (const float*)d_in[2];
    const float* Wo  = (const float*)d_in[3];
    const float* bo  = (const float*)d_in[4];
    float* out = (float*)d_out;

    const size_t SEG = (size_t)8388608 * 2;   // 16 MB per bf16 [8192x1024]
    char* ws = (char*)d_ws;
    ushort* xb = (ushort*)(ws);
    ushort* Qb = (ushort*)(ws + SEG);
    ushort* Kb = (ushort*)(ws + SEG * 2);
    ushort* Vt = (ushort*)(ws + SEG * 3);     // [bh*64+d][2048]
    ushort* Ob = (ushort*)(ws + SEG * 4);
    ushort* Wt = (ushort*)(ws + SEG * 5);     // [4096][1024] bf16

    convert_x<<<dim3(4096), 256, 0, stream>>>(x, xb);
    prep_w<<<dim3(256), 256, 0, stream>>>(Wq, Wkv, Wo, Wt);
    gemm_qkv<<<dim3(24, 64), 256, 0, stream>>>(xb, Wt, Qb, Kb, Vt);
    flash_mfma<<<dim3(1024), 256, 0, stream>>>(Qb, Kb, Vt, Ob);
    gemm_out<<<dim3(8, 64), 256, 0, stream>>>(Ob, Wt + (size_t)3072 * 1024, bo, out);
}